// Round 18
// baseline (204.298 us; speedup 1.0000x reference)
//
#include <hip/hip_runtime.h>

// RegionSeparatedAttention on MI355X — round 18: BARRIER-FREE k_attn K-loop.
// r14's wave layout (wj path x jsw slab-half, 2 m-frag sets/wave) makes all
// K-loop data wave-private, so the per-slab __syncthreads (whose compiler-
// emitted s_waitcnt vmcnt(0) drains the prefetch — the documented m97
// plateau) is replaced by a per-wave s_waitcnt vmcnt(8): the 8 stage16s for
// round+1 stay in flight while round is computed (AITER-style pipeline).
// Each wave stages its own 8 KB/round into a private 2x8KB dbuf (64 KB
// block LDS, 2 blocks/CU).  Math/data/epilogue = r14 green VERBATIM.
// All other kernels r13/r14 green VERBATIM.
//
// Global layouts in ws (per region br = b*4 + gi*2 + gj), ALL pre-swizzled:
//   Qp,Kp : bf16 [8][4096 n][64 c] pixel-major rows, seg' = seg ^ (n & 7)
//           (Q pre-scaled by 0.125*log2e)
//   Atl,Btl: bf16 [8][128 jtile][64 c][32 j], seg' = seg ^ ((c>>1) & 3)
//           (A gets *= Linv[j] in k_ascale)
//   OutP  : bf16 [8][4096 n][64 c] pixel-major, UNswizzled
//   Linv  : f32 [8][4096]   (1 / softmax row sum, from k_ascale)
//   Lpart : f32 [2 ms][8][4096] partial row sums (k_stats)

typedef __attribute__((ext_vector_type(8)))  short bf16x8;
typedef __attribute__((ext_vector_type(16))) float f32x16;

#define MFMA32(a, b, c) __builtin_amdgcn_mfma_f32_32x32x16_bf16(a, b, c, 0, 0, 0)

constexpr int REG_ELEMS = 4096 * 64;
constexpr size_t QP_OFF    = 0;
constexpr size_t KP_OFF    = 4u  << 20;
constexpr size_t ATL_OFF   = 8u  << 20;
constexpr size_t BTL_OFF   = 12u << 20;
constexpr size_t OUTP_OFF  = 16u << 20;
constexpr size_t LNV_OFF   = 20u << 20;                  // f32 [8][4096]
constexpr size_t LPART_OFF = (20u << 20) + (128u << 10); // f32 [2][8][4096]

constexpr float QSCALE = 0.18033688011112042f;  // 0.125 * log2(e)

__device__ __forceinline__ short f2bf(float f) {   // RNE
    union { float f; unsigned u; } v; v.f = f;
    unsigned r = v.u + 0x7fffu + ((v.u >> 16) & 1u);
    return (short)(r >> 16);
}
__device__ __forceinline__ float bf2f(short s) {
    union { unsigned u; float f; } v; v.u = ((unsigned)(unsigned short)s) << 16;
    return v.f;
}
__device__ __forceinline__ unsigned fbits(float f) {
    union { float f; unsigned u; } v; v.f = f; return v.u;
}
__device__ __forceinline__ unsigned pack_trunc(float e0, float e1) {
    return __builtin_amdgcn_perm(fbits(e1), fbits(e0), 0x07060302u);
}
__device__ __forceinline__ f32x16 zero16() {
    f32x16 z;
    #pragma unroll
    for (int i = 0; i < 16; ++i) z[i] = 0.f;
    return z;
}
__device__ __forceinline__ float fexp2(float x) {
#if __has_builtin(__builtin_amdgcn_exp2f)
    return __builtin_amdgcn_exp2f(x);
#else
    return exp2f(x);
#endif
}
__device__ __forceinline__ void permswap32(unsigned& a, unsigned& b, bool hi) {
#if __has_builtin(__builtin_amdgcn_permlane32_swap)
    auto r = __builtin_amdgcn_permlane32_swap(a, b, false, false);
    a = r[0]; b = r[1];
#elif __has_builtin(__builtin_amdgcn_permlane32_swap_b32)
    auto r = __builtin_amdgcn_permlane32_swap_b32(a, b, false, false);
    a = r[0]; b = r[1];
#else
    unsigned ax = (unsigned)__shfl_xor((int)a, 32);
    unsigned bx = (unsigned)__shfl_xor((int)b, 32);
    unsigned na = hi ? bx : a;
    unsigned nb = hi ? b  : ax;
    a = na; b = nb;
#endif
}

typedef __attribute__((address_space(1))) const unsigned char as1_t;
typedef __attribute__((address_space(3))) unsigned char as3_t;
__device__ __forceinline__ void stage16(const void* g, void* l) {
    __builtin_amdgcn_global_load_lds((as1_t*)g, (as3_t*)l, 16, 0, 0);
}

// ---------------------------------------------------------------- k_conv_in
// (round-8/13 green verbatim)
__global__ __launch_bounds__(256) void k_conv_in(
    const float* __restrict__ x,
    const float* __restrict__ Wq, const float* __restrict__ bq,
    const float* __restrict__ Wk, const float* __restrict__ bk,
    const float* __restrict__ Wa, const float* __restrict__ ba,
    const float* __restrict__ Wb, const float* __restrict__ bb,
    char* __restrict__ ws)
{
    const int tid  = threadIdx.x;
    const int blk  = blockIdx.x;
    const int wseg = blk & 1;
    const int h    = (blk >> 1) & 127;
    const int b    = blk >> 8;
    const int br   = b * 4 + (h >> 6) * 2 + wseg;
    const int n0   = (h & 63) * 64;

    __shared__ float xs[64][68];               // [c][px]
    __shared__ short trans[2][64][72];         // [mat][px][oc]

    const float* xp = x + ((size_t)b * 64 * 16384) + (size_t)h * 128 + wseg * 64;
    #pragma unroll
    for (int r = 0; r < 4; ++r) {
        int idx = r * 256 + tid;
        int c   = idx >> 4;
        int w4  = (idx & 15) << 2;
        *(float4*)&xs[c][w4] = *(const float4*)(xp + (size_t)c * 16384 + w4);
    }
    __syncthreads();

    const int lane = tid & 63;
    const int wid  = tid >> 6;
    const int col  = lane & 31;
    const int l5   = lane >> 5;
    const int pH   = wid & 1;                  // pixel half
    const int oH   = wid >> 1;                 // oc half
    const int px   = pH * 32 + col;
    const int oc   = oH * 32 + col;

    bf16x8 xhi[4], xlo[4];
    #pragma unroll
    for (int s = 0; s < 4; ++s) {
        union { bf16x8 v; short sh[8]; } uh, ul;
        #pragma unroll
        for (int e = 0; e < 8; ++e) {
            float xv = xs[s * 16 + l5 * 8 + e][px];
            short hh = f2bf(xv);
            uh.sh[e] = hh;
            ul.sh[e] = f2bf(xv - bf2f(hh));
        }
        xhi[s] = uh.v; xlo[s] = ul.v;
    }

    #pragma unroll
    for (int mat = 0; mat < 4; ++mat) {
        const float* Wsel = (mat == 0) ? Wq : (mat == 1) ? Wk : (mat == 2) ? Wa : Wb;
        const float* bsel = (mat == 0) ? bq : (mat == 1) ? bk : (mat == 2) ? ba : bb;

        bf16x8 whi[4], wlo[4];
        const float* wrow = Wsel + (size_t)oc * 64;
        #pragma unroll
        for (int s = 0; s < 4; ++s) {
            float4 f0 = *(const float4*)(wrow + s * 16 + l5 * 8);
            float4 f1 = *(const float4*)(wrow + s * 16 + l5 * 8 + 4);
            float wf[8] = { f0.x, f0.y, f0.z, f0.w, f1.x, f1.y, f1.z, f1.w };
            union { bf16x8 v; short sh[8]; } uh, ul;
            #pragma unroll
            for (int e = 0; e < 8; ++e) {
                short hh = f2bf(wf[e]);
                uh.sh[e] = hh;
                ul.sh[e] = f2bf(wf[e] - bf2f(hh));
            }
            whi[s] = uh.v; wlo[s] = ul.v;
        }

        f32x16 d = zero16();
        #pragma unroll
        for (int s = 0; s < 4; ++s) {
            d = MFMA32(xhi[s], whi[s], d);
            d = MFMA32(xhi[s], wlo[s], d);
            d = MFMA32(xlo[s], whi[s], d);
        }

        const float bias = bsel[oc];
        if (mat < 2) {
            const float sc = (mat == 0) ? QSCALE : 1.0f;
            #pragma unroll
            for (int r = 0; r < 16; ++r) {
                int pxl = pH * 32 + (r & 3) + 8 * (r >> 2) + 4 * l5;
                trans[mat][pxl][oc] = f2bf((d[r] + bias) * sc);
            }
        } else {
            short* base = (short*)(ws + (mat == 2 ? ATL_OFF : BTL_OFF))
                          + (size_t)br * REG_ELEMS;
            const int sw   = (oc >> 1) & 3;
            const int tile = (n0 >> 5) + pH;
            #pragma unroll
            for (int q = 0; q < 4; ++q) {
                short tmp4[4];
                #pragma unroll
                for (int rr = 0; rr < 4; ++rr) tmp4[rr] = f2bf(d[4 * q + rr] + bias);
                int segp = q ^ sw;
                short* p = base + (size_t)tile * 2048 + oc * 32 + segp * 8 + 4 * l5;
                *(uint2*)p = *(uint2*)tmp4;
            }
        }
    }
    __syncthreads();

    #pragma unroll
    for (int rep = 0; rep < 4; ++rep) {
        int idx  = rep * 256 + tid;
        int mat2 = idx >> 9;
        int row  = (idx >> 3) & 63;
        int seg  = idx & 7;
        short* dst = (short*)(ws + (mat2 ? KP_OFF : QP_OFF))
                     + (size_t)br * REG_ELEMS + (size_t)(n0 + row) * 64
                     + (seg ^ (row & 7)) * 8;
        *(uint4*)dst = *(uint4*)&trans[mat2][row][seg * 8];
    }
}

// ------------------------------------------------------------------ k_stats
// (r13 green m-split verbatim)
__global__ __launch_bounds__(256, 2) void k_stats(char* __restrict__ ws)
{
    const int tid  = threadIdx.x;
    const int br   = blockIdx.x & 7;
    const int nt   = (blockIdx.x >> 3) & 63;
    const int ms   = blockIdx.x >> 9;          // m-half
    const int lane = tid & 63;
    const int w    = tid >> 6;
    const int wn   = w & 1;
    const int wi   = w >> 1;
    const int col  = lane & 31;
    const int l5   = lane >> 5;

    const short* Qb  = (const short*)(ws + QP_OFF) + (size_t)br * REG_ELEMS;
    const char*  Kbb = ws + KP_OFF + (size_t)br * REG_ELEMS * 2
                       + (size_t)ms * 262144;  // 2048 rows * 128 B

    __shared__ __align__(16) char smem[16896];  // dbuf 16K | Lred 512

    const int nrow = nt * 64 + wn * 32 + col;
    bf16x8 afr[4];
    #pragma unroll
    for (int s = 0; s < 4; ++s)
        afr[s] = *(const bf16x8*)(Qb + (size_t)nrow * 64 + (((2*s+l5) ^ (col & 7)) * 8));

    float sm[16];
    #pragma unroll
    for (int r = 0; r < 16; ++r) sm[r] = 0.f;

    {   // stage slab 0 (64 m-rows = 8 KB; wave w covers 2 KB)
        const char* g = Kbb + (size_t)w * 2048 + lane * 16;
        char* l = smem + w * 2048;
        stage16(g, l); stage16(g + 1024, l + 1024);
    }

    #pragma unroll 2
    for (int slab = 0; slab < 32; ++slab) {
        __syncthreads();
        if (slab + 1 < 32) {
            const char* g = Kbb + (size_t)(slab + 1) * 8192 + w * 2048 + lane * 16;
            char* l = smem + ((slab + 1) & 1) * 8192 + w * 2048;
            stage16(g, l); stage16(g + 1024, l + 1024);
        }
        const short* Ks = (const short*)(smem + (slab & 1) * 8192);
        f32x16 d = zero16();
        #pragma unroll
        for (int s = 0; s < 4; ++s) {
            bf16x8 bf = *(const bf16x8*)(Ks + (wi * 32 + col) * 64
                                         + ((2*s+l5) ^ (col & 7)) * 8);
            d = MFMA32(afr[s], bf, d);
        }
        #pragma unroll
        for (int r = 0; r < 16; ++r) sm[r] += fexp2(d[r]);
    }

    #pragma unroll
    for (int off = 1; off < 32; off <<= 1)
        #pragma unroll
        for (int r = 0; r < 16; ++r) sm[r] += __shfl_xor(sm[r], off);

    __syncthreads();
    float* Lred = (float*)(smem + 16384);      // [4][32]
    if (col == 0) {
        #pragma unroll
        for (int r = 0; r < 16; ++r)
            Lred[w * 32 + ((r & 3) + 8 * (r >> 2) + 4 * l5)] = sm[r];
    }
    __syncthreads();
    if (tid < 64) {
        int wn2 = tid >> 5, nl = tid & 31;
        float L = Lred[wn2 * 32 + nl] + Lred[(wn2 + 2) * 32 + nl];
        ((float*)(ws + LPART_OFF))[(size_t)ms * 32768 + (size_t)br * 4096
                                   + nt * 64 + tid] = L;
    }
}

// ------------------------------------------------------------------ k_ascale
// (r13 green verbatim)
__global__ __launch_bounds__(256) void k_ascale(char* __restrict__ ws)
{
    const int tid = threadIdx.x;
    const int br  = blockIdx.x & 7;
    const int nt  = blockIdx.x >> 3;           // 0..63

    __shared__ float Larr[64];

    if (tid < 64) {
        const float* Lp = (const float*)(ws + LPART_OFF);
        const size_t idx = (size_t)br * 4096 + nt * 64 + tid;
        float li = 1.0f / (Lp[idx] + Lp[32768 + idx]);
        Larr[tid] = li;
        ((float*)(ws + LNV_OFF))[idx] = li;
    }
    __syncthreads();

    short* Ab = (short*)(ws + ATL_OFF) + (size_t)br * REG_ELEMS + (size_t)nt * 4096;
    #pragma unroll
    for (int rep = 0; rep < 2; ++rep) {
        int id = rep * 256 + tid;              // 0..511 chunks of 16B
        int t = id >> 8, c = (id >> 2) & 63, s = id & 3;
        int sg = s ^ ((c >> 1) & 3);
        int jl = t * 32 + sg * 8;
        short* p = Ab + (size_t)t * 2048 + c * 32 + s * 8;
        uint4 v = *(uint4*)p;
        short* sp = (short*)&v;
        short o[8];
        #pragma unroll
        for (int e = 0; e < 8; ++e) o[e] = f2bf(bf2f(sp[e]) * Larr[jl + e]);
        *(uint4*)p = *(uint4*)o;
    }
}

// ------------------------------------------------------------------- k_attn
// r14 math/layout verbatim; staging made WAVE-PRIVATE (each wave stages its
// own jr+ts 8 KB/round into a private 2x8KB dbuf) -> no __syncthreads in the
// K-loop; inter-round sync is per-wave s_waitcnt vmcnt(8) (prefetch for
// round+1 stays in flight).  4 waves = (wj path) x (jsw slab-half); each
// wave holds 2 m-frag sets + 4 accumulators.  One barrier before epilogue.
__global__ __launch_bounds__(256, 2) void k_attn(char* __restrict__ ws)
{
    const int tid  = threadIdx.x;
    const int br   = blockIdx.x & 7;
    const int mt   = blockIdx.x >> 3;          // 0..63, m-tile of 64
    const int lane = tid & 63;
    const int w    = tid >> 6;                 // 0..3
    const int wj   = w & 1;                    // path: 0 = G1*A', 1 = G2*B
    const int jsw  = w >> 1;                   // slab-half this wave computes
    const int col  = lane & 31;
    const int l5   = lane >> 5;
    const bool hi  = (l5 != 0);

    const char* Qbb = ws + QP_OFF  + (size_t)br * REG_ELEMS * 2;
    const char* Kbb = ws + KP_OFF  + (size_t)br * REG_ELEMS * 2;
    const char* Abb = ws + ATL_OFF + (size_t)br * REG_ELEMS * 2;
    const char* Bbb = ws + BTL_OFF + (size_t)br * REG_ELEMS * 2;
    const float* Lnv = (const float*)(ws + LNV_OFF) + (size_t)br * 4096;
    short* OutPb    = (short*)(ws + OUTP_OFF) + (size_t)br * REG_ELEMS;

    __shared__ __align__(16) char smem[65536];  // 4 waves x 2 x 8KB; red overlay

    // both m-fragment sets (m-sub 0 and 1)  — r14 verbatim
    const short* msrcb = (const short*)(wj == 0 ? Kbb : Qbb);
    bf16x8 mf[2][4];
    #pragma unroll
    for (int h = 0; h < 2; ++h) {
        const short* mr = msrcb + (size_t)(mt * 64 + h * 32 + col) * 64;
        #pragma unroll
        for (int s = 0; s < 4; ++s)
            mf[h][s] = *(const bf16x8*)(mr + ((2*s+l5) ^ (col & 7)) * 8);
    }

    f32x16 acc00 = zero16(), acc01 = zero16();  // m-sub0: cols 0-31 / 32-63
    f32x16 acc10 = zero16(), acc11 = zero16();  // m-sub1

    // wave-private staging sources: jr = Q|K rows, ts = A'|B tile
    const char* gj = (wj == 0) ? Qbb : Kbb;
    const char* gt = (wj == 0) ? Abb : Bbb;
    char* myb = smem + w * 16384;

    {   // stage round 0 (slab = jsw)
        const char* gjs = gj + (size_t)jsw * 4096 + lane * 16;
        const char* gts = gt + (size_t)jsw * 4096 + lane * 16;
        char* l = myb + lane * 16;
        #pragma unroll
        for (int i = 0; i < 4; ++i) stage16(gjs + i * 1024, l + i * 1024);
        #pragma unroll
        for (int i = 0; i < 4; ++i) stage16(gts + i * 1024, l + 4096 + i * 1024);
    }

    #pragma unroll 2
    for (int rnd = 0; rnd < 64; ++rnd) {
        if (rnd + 1 < 64) {
            const int slab = 2 * (rnd + 1) + jsw;
            const char* gjs = gj + (size_t)slab * 4096 + lane * 16;
            const char* gts = gt + (size_t)slab * 4096 + lane * 16;
            char* l = myb + ((rnd + 1) & 1) * 8192 + lane * 16;
            #pragma unroll
            for (int i = 0; i < 4; ++i) stage16(gjs + i * 1024, l + i * 1024);
            #pragma unroll
            for (int i = 0; i < 4; ++i) stage16(gts + i * 1024, l + 4096 + i * 1024);
            __builtin_amdgcn_s_waitcnt(0x0F78);  // vmcnt<=8: this round's done
        } else {
            __builtin_amdgcn_s_waitcnt(0x0F70);  // vmcnt(0): last round
        }

        const char* sb = myb + (rnd & 1) * 8192;
        const short* jr = (const short*)sb;            // Q | K rows (this wave)
        const short* ts = (const short*)(sb + 4096);   // A' | B tile

        // one set of jr reads serves both m-halves  — r14 verbatim
        bf16x8 a[4];
        #pragma unroll
        for (int s = 0; s < 4; ++s)
            a[s] = *(const bf16x8*)(jr + col * 64 + ((2*s+l5) ^ (col & 7)) * 8);

        f32x16 d0 = zero16(), d1 = zero16();
        #pragma unroll
        for (int s = 0; s < 4; ++s) {
            d0 = MFMA32(a[s], mf[0][s], d0);
            d1 = MFMA32(a[s], mf[1][s], d1);
        }

        unsigned W0[8], W1[8];
        #pragma unroll
        for (int q = 0; q < 4; ++q) {
            W0[2*q]   = pack_trunc(fexp2(d0[4*q]),   fexp2(d0[4*q+1]));
            W0[2*q+1] = pack_trunc(fexp2(d0[4*q+2]), fexp2(d0[4*q+3]));
            W1[2*q]   = pack_trunc(fexp2(d1[4*q]),   fexp2(d1[4*q+1]));
            W1[2*q+1] = pack_trunc(fexp2(d1[4*q+2]), fexp2(d1[4*q+3]));
        }

        #pragma unroll
        for (int k16 = 0; k16 < 2; ++k16) {
            unsigned u0 = W0[4*k16+0], u1 = W0[4*k16+1];
            unsigned u2 = W0[4*k16+2], u3 = W0[4*k16+3];
            permswap32(u0, u2, hi);
            permswap32(u1, u3, hi);
            union { uint4 u; bf16x8 v; } fr0;
            fr0.u.x = u0; fr0.u.y = u1; fr0.u.z = u2; fr0.u.w = u3;

            unsigned v0 = W1[4*k16+0], v1 = W1[4*k16+1];
            unsigned v2 = W1[4*k16+2], v3 = W1[4*k16+3];
            permswap32(v0, v2, hi);
            permswap32(v1, v3, hi);
            union { uint4 u; bf16x8 v; } fr1;
            fr1.u.x = v0; fr1.u.y = v1; fr1.u.z = v2; fr1.u.w = v3;

            const int swz = ((2*k16 + l5) ^ ((col >> 1) & 3)) * 8;
            bf16x8 bL = *(const bf16x8*)(ts + col * 32 + swz);
            bf16x8 bH = *(const bf16x8*)(ts + (col + 32) * 32 + swz);
            acc00 = MFMA32(fr0.v, bL, acc00);
            acc01 = MFMA32(fr0.v, bH, acc01);
            acc10 = MFMA32(fr1.v, bL, acc10);
            acc11 = MFMA32(fr1.v, bH, acc11);
        }
    }

    // epilogue: f32 combine across waves (r14 green verbatim)
    __syncthreads();
    float* red = (float*)smem;                 // [64][68]
    if (w == 0) {
        #pragma unroll
        for (int h = 0; h < 2; ++h)
            #pragma unroll
            for (int r = 0; r < 16; ++r) {
                int ml = h * 32 + (r & 3) + 8 * (r >> 2) + 4 * l5;
                red[ml * 68 + col]      = h ? acc10[r] : acc00[r];
                red[ml * 68 + 32 + col] = h ? acc11[r] : acc01[r];
            }
    }
    __syncthreads();
    if (w == 2) {
        #pragma unroll
        for (int h = 0; h < 2; ++h)
            #pragma unroll
            for (int r = 0; r < 16; ++r) {
                int ml = h * 32 + (r & 3) + 8 * (r >> 2) + 4 * l5;
                red[ml * 68 + col]      += h ? acc10[r] : acc00[r];
                red[ml * 68 + 32 + col] += h ? acc11[r] : acc01[r];
            }
    }
    __syncthreads();
    if (w == 1) {
        #pragma unroll
        for (int h = 0; h < 2; ++h)
            #pragma unroll
            for (int r = 0; r < 16; ++r) {
                int ml = h * 32 + (r & 3) + 8 * (r >> 2) + 4 * l5;
                float li = Lnv[mt * 64 + ml];
                red[ml * 68 + col]      += li * (h ? acc10[r] : acc00[r]);
                red[ml * 68 + 32 + col] += li * (h ? acc11[r] : acc01[r]);
            }
    }
    __syncthreads();
    if (w == 3) {
        #pragma unroll
        for (int h = 0; h < 2; ++h)
            #pragma unroll
            for (int r = 0; r < 16; ++r) {
                int ml = h * 32 + (r & 3) + 8 * (r >> 2) + 4 * l5;
                float li = Lnv[mt * 64 + ml];
                red[ml * 68 + col]      += li * (h ? acc10[r] : acc00[r]);
                red[ml * 68 + 32 + col] += li * (h ? acc11[r] : acc01[r]);
            }
    }
    __syncthreads();
    {
        const int m  = tid >> 2;
        const int c0 = (tid & 3) * 16;
        const float* rp = red + m * 68 + c0;
        uint4 p0, p1;
        p0.x = pack_trunc(rp[0],  rp[1]);  p0.y = pack_trunc(rp[2],  rp[3]);
        p0.z = pack_trunc(rp[4],  rp[5]);  p0.w = pack_trunc(rp[6],  rp[7]);
        p1.x = pack_trunc(rp[8],  rp[9]);  p1.y = pack_trunc(rp[10], rp[11]);
        p1.z = pack_trunc(rp[12], rp[13]); p1.w = pack_trunc(rp[14], rp[15]);
        short* orow = OutPb + (size_t)(mt * 64 + m) * 64 + c0;
        *(uint4*)orow       = p0;
        *(uint4*)(orow + 8) = p1;
    }
}

// --------------------------------------------------------------- k_conv_out
// (r13/r14 green verbatim: 256-thread remap, single OutP)
__global__ __launch_bounds__(256) void k_conv_out(
    const char* __restrict__ ws,
    const float* __restrict__ Wo, const float* __restrict__ bo,
    float* __restrict__ out)
{
    const int tid  = threadIdx.x;
    const int lane = tid & 63;
    const int sub  = tid >> 6;                 // 0..3
    const int blk  = blockIdx.x;               // 0..255
    const int br   = blk & 7;
    const int nt   = (blk >> 3) * 4 + sub;     // 0..127
    const int col  = lane & 31;
    const int l5   = lane >> 5;

    const short* OutPb = (const short*)(ws + OUTP_OFF) + (size_t)br * REG_ELEMS;

    bf16x8 afr[4];
    const short* arow = OutPb + (size_t)(nt * 32 + col) * 64 + l5 * 8;
    #pragma unroll
    for (int s = 0; s < 4; ++s) afr[s] = *(const bf16x8*)(arow + s * 16);

    bf16x8 bw[2][4];
    #pragma unroll
    for (int oh = 0; oh < 2; ++oh) {
        const float* wrow = Wo + (size_t)(oh * 32 + col) * 64 + l5 * 8;
        #pragma unroll
        for (int s = 0; s < 4; ++s) {
            float4 f0 = *(const float4*)(wrow + s * 16);
            float4 f1 = *(const float4*)(wrow + s * 16 + 4);
            union { bf16x8 v; short sh[8]; } u;
            u.sh[0] = f2bf(f0.x); u.sh[1] = f2bf(f0.y);
            u.sh[2] = f2bf(f0.z); u.sh[3] = f2bf(f0.w);
            u.sh[4] = f2bf(f1.x); u.sh[5] = f2bf(f1.y);
            u.sh[6] = f2bf(f1.z); u.sh[7] = f2bf(f1.w);
            bw[oh][s] = u.v;
        }
    }

    f32x16 d0 = zero16(), d1 = zero16();
    #pragma unroll
    for (int s = 0; s < 4; ++s) {
        d0 = MFMA32(afr[s], bw[0][s], d0);
        d1 = MFMA32(afr[s], bw[1][s], d1);
    }

    const int b  = br >> 2;
    const int gi = (br >> 1) & 1;
    const int gj = br & 1;

    #pragma unroll
    for (int oh = 0; oh < 2; ++oh) {
        const int oc = oh * 32 + col;
        const float bias = bo[oc];
        const f32x16& d = oh ? d1 : d0;
        #pragma unroll
        for (int q = 0; q < 4; ++q) {
            int nloc = 8 * q + 4 * l5;
            int nreg = nt * 32 + nloc;
            int wp   = nreg & 63;
            int ip   = nreg >> 6;
            float4 v = make_float4(d[4*q+0] + bias, d[4*q+1] + bias,
                                   d[4*q+2] + bias, d[4*q+3] + bias);
            float* op = out + ((size_t)(b * 64 + oc)) * 16384
                        + (size_t)(gi * 64 + ip) * 128 + gj * 64 + wp;
            *(float4*)op = v;
        }
    }
}

// -------------------------------------------------------------------- launch
extern "C" void kernel_launch(void* const* d_in, const int* in_sizes, int n_in,
                              void* d_out, int out_size, void* d_ws, size_t ws_size,
                              hipStream_t stream)
{
    const float* x  = (const float*)d_in[0];
    const float* Wq = (const float*)d_in[1];
    const float* bq = (const float*)d_in[2];
    const float* Wk = (const float*)d_in[3];
    const float* bk = (const float*)d_in[4];
    const float* Wa = (const float*)d_in[5];
    const float* ba = (const float*)d_in[6];
    const float* Wb = (const float*)d_in[7];
    const float* bb = (const float*)d_in[8];
    const float* Wo = (const float*)d_in[9];
    const float* bo = (const float*)d_in[10];
    char* ws   = (char*)d_ws;
    float* out = (float*)d_out;

    hipLaunchKernelGGL(k_conv_in,  dim3(512),  dim3(256), 0, stream,
                       x, Wq, bq, Wk, bk, Wa, ba, Wb, bb, ws);
    hipLaunchKernelGGL(k_stats,    dim3(1024), dim3(256), 0, stream, ws);
    hipLaunchKernelGGL(k_ascale,   dim3(512),  dim3(256), 0, stream, ws);
    hipLaunchKernelGGL(k_attn,     dim3(512),  dim3(256), 0, stream, ws);
    hipLaunchKernelGGL(k_conv_out, dim3(256),  dim3(256), 0, stream,
                       ws, Wo, bo, out);
}

// Round 19
// 201.738 us; speedup vs baseline: 1.0127x; 1.0127x over previous
//
#include <hip/hip_runtime.h>

// RegionSeparatedAttention on MI355X — round 19: FINAL lock-in of the
// measured-best configuration (round 14 verbatim, 202.7 us).
//
// Convergence evidence: k_attn is bounded at ~82-88 us across four green
// structural variants (barriers / no barriers / js-split / jsw-split /
// halved LDS reads) — all consistent with the measured global_load_lds
// staging ceiling (~1 GB staged / ~11.5-12 TB/s ≈ 85 us).  Staged-byte
// halving (m-tile 128) failed 3x (spills or audit-clean miscompare).
// Pipeline total plateau: 202.7-204.3 us over the last 5 green rounds.
//
// Global layouts in ws (per region br = b*4 + gi*2 + gj), ALL pre-swizzled:
//   Qp,Kp : bf16 [8][4096 n][64 c] pixel-major rows, seg' = seg ^ (n & 7)
//           (Q pre-scaled by 0.125*log2e)
//   Atl,Btl: bf16 [8][128 jtile][64 c][32 j], seg' = seg ^ ((c>>1) & 3)
//           (A gets *= Linv[j] in k_ascale)
//   OutP  : bf16 [8][4096 n][64 c] pixel-major, UNswizzled
//   Linv  : f32 [8][4096]   (1 / softmax row sum, from k_ascale)
//   Lpart : f32 [2 ms][8][4096] partial row sums (k_stats)

typedef __attribute__((ext_vector_type(8)))  short bf16x8;
typedef __attribute__((ext_vector_type(16))) float f32x16;

#define MFMA32(a, b, c) __builtin_amdgcn_mfma_f32_32x32x16_bf16(a, b, c, 0, 0, 0)

constexpr int REG_ELEMS = 4096 * 64;
constexpr size_t QP_OFF    = 0;
constexpr size_t KP_OFF    = 4u  << 20;
constexpr size_t ATL_OFF   = 8u  << 20;
constexpr size_t BTL_OFF   = 12u << 20;
constexpr size_t OUTP_OFF  = 16u << 20;
constexpr size_t LNV_OFF   = 20u << 20;                  // f32 [8][4096]
constexpr size_t LPART_OFF = (20u << 20) + (128u << 10); // f32 [2][8][4096]

constexpr float QSCALE = 0.18033688011112042f;  // 0.125 * log2(e)

__device__ __forceinline__ short f2bf(float f) {   // RNE
    union { float f; unsigned u; } v; v.f = f;
    unsigned r = v.u + 0x7fffu + ((v.u >> 16) & 1u);
    return (short)(r >> 16);
}
__device__ __forceinline__ float bf2f(short s) {
    union { unsigned u; float f; } v; v.u = ((unsigned)(unsigned short)s) << 16;
    return v.f;
}
__device__ __forceinline__ unsigned fbits(float f) {
    union { float f; unsigned u; } v; v.f = f; return v.u;
}
__device__ __forceinline__ unsigned pack_trunc(float e0, float e1) {
    return __builtin_amdgcn_perm(fbits(e1), fbits(e0), 0x07060302u);
}
__device__ __forceinline__ f32x16 zero16() {
    f32x16 z;
    #pragma unroll
    for (int i = 0; i < 16; ++i) z[i] = 0.f;
    return z;
}
__device__ __forceinline__ float fexp2(float x) {
#if __has_builtin(__builtin_amdgcn_exp2f)
    return __builtin_amdgcn_exp2f(x);
#else
    return exp2f(x);
#endif
}
__device__ __forceinline__ void permswap32(unsigned& a, unsigned& b, bool hi) {
#if __has_builtin(__builtin_amdgcn_permlane32_swap)
    auto r = __builtin_amdgcn_permlane32_swap(a, b, false, false);
    a = r[0]; b = r[1];
#elif __has_builtin(__builtin_amdgcn_permlane32_swap_b32)
    auto r = __builtin_amdgcn_permlane32_swap_b32(a, b, false, false);
    a = r[0]; b = r[1];
#else
    unsigned ax = (unsigned)__shfl_xor((int)a, 32);
    unsigned bx = (unsigned)__shfl_xor((int)b, 32);
    unsigned na = hi ? bx : a;
    unsigned nb = hi ? b  : ax;
    a = na; b = nb;
#endif
}

typedef __attribute__((address_space(1))) const unsigned char as1_t;
typedef __attribute__((address_space(3))) unsigned char as3_t;
__device__ __forceinline__ void stage16(const void* g, void* l) {
    __builtin_amdgcn_global_load_lds((as1_t*)g, (as3_t*)l, 16, 0, 0);
}

// ---------------------------------------------------------------- k_conv_in
// (round-8/13 green verbatim)
__global__ __launch_bounds__(256) void k_conv_in(
    const float* __restrict__ x,
    const float* __restrict__ Wq, const float* __restrict__ bq,
    const float* __restrict__ Wk, const float* __restrict__ bk,
    const float* __restrict__ Wa, const float* __restrict__ ba,
    const float* __restrict__ Wb, const float* __restrict__ bb,
    char* __restrict__ ws)
{
    const int tid  = threadIdx.x;
    const int blk  = blockIdx.x;
    const int wseg = blk & 1;
    const int h    = (blk >> 1) & 127;
    const int b    = blk >> 8;
    const int br   = b * 4 + (h >> 6) * 2 + wseg;
    const int n0   = (h & 63) * 64;

    __shared__ float xs[64][68];               // [c][px]
    __shared__ short trans[2][64][72];         // [mat][px][oc]

    const float* xp = x + ((size_t)b * 64 * 16384) + (size_t)h * 128 + wseg * 64;
    #pragma unroll
    for (int r = 0; r < 4; ++r) {
        int idx = r * 256 + tid;
        int c   = idx >> 4;
        int w4  = (idx & 15) << 2;
        *(float4*)&xs[c][w4] = *(const float4*)(xp + (size_t)c * 16384 + w4);
    }
    __syncthreads();

    const int lane = tid & 63;
    const int wid  = tid >> 6;
    const int col  = lane & 31;
    const int l5   = lane >> 5;
    const int pH   = wid & 1;                  // pixel half
    const int oH   = wid >> 1;                 // oc half
    const int px   = pH * 32 + col;
    const int oc   = oH * 32 + col;

    bf16x8 xhi[4], xlo[4];
    #pragma unroll
    for (int s = 0; s < 4; ++s) {
        union { bf16x8 v; short sh[8]; } uh, ul;
        #pragma unroll
        for (int e = 0; e < 8; ++e) {
            float xv = xs[s * 16 + l5 * 8 + e][px];
            short hh = f2bf(xv);
            uh.sh[e] = hh;
            ul.sh[e] = f2bf(xv - bf2f(hh));
        }
        xhi[s] = uh.v; xlo[s] = ul.v;
    }

    #pragma unroll
    for (int mat = 0; mat < 4; ++mat) {
        const float* Wsel = (mat == 0) ? Wq : (mat == 1) ? Wk : (mat == 2) ? Wa : Wb;
        const float* bsel = (mat == 0) ? bq : (mat == 1) ? bk : (mat == 2) ? ba : bb;

        bf16x8 whi[4], wlo[4];
        const float* wrow = Wsel + (size_t)oc * 64;
        #pragma unroll
        for (int s = 0; s < 4; ++s) {
            float4 f0 = *(const float4*)(wrow + s * 16 + l5 * 8);
            float4 f1 = *(const float4*)(wrow + s * 16 + l5 * 8 + 4);
            float wf[8] = { f0.x, f0.y, f0.z, f0.w, f1.x, f1.y, f1.z, f1.w };
            union { bf16x8 v; short sh[8]; } uh, ul;
            #pragma unroll
            for (int e = 0; e < 8; ++e) {
                short hh = f2bf(wf[e]);
                uh.sh[e] = hh;
                ul.sh[e] = f2bf(wf[e] - bf2f(hh));
            }
            whi[s] = uh.v; wlo[s] = ul.v;
        }

        f32x16 d = zero16();
        #pragma unroll
        for (int s = 0; s < 4; ++s) {
            d = MFMA32(xhi[s], whi[s], d);
            d = MFMA32(xhi[s], wlo[s], d);
            d = MFMA32(xlo[s], whi[s], d);
        }

        const float bias = bsel[oc];
        if (mat < 2) {
            const float sc = (mat == 0) ? QSCALE : 1.0f;
            #pragma unroll
            for (int r = 0; r < 16; ++r) {
                int pxl = pH * 32 + (r & 3) + 8 * (r >> 2) + 4 * l5;
                trans[mat][pxl][oc] = f2bf((d[r] + bias) * sc);
            }
        } else {
            short* base = (short*)(ws + (mat == 2 ? ATL_OFF : BTL_OFF))
                          + (size_t)br * REG_ELEMS;
            const int sw   = (oc >> 1) & 3;
            const int tile = (n0 >> 5) + pH;
            #pragma unroll
            for (int q = 0; q < 4; ++q) {
                short tmp4[4];
                #pragma unroll
                for (int rr = 0; rr < 4; ++rr) tmp4[rr] = f2bf(d[4 * q + rr] + bias);
                int segp = q ^ sw;
                short* p = base + (size_t)tile * 2048 + oc * 32 + segp * 8 + 4 * l5;
                *(uint2*)p = *(uint2*)tmp4;
            }
        }
    }
    __syncthreads();

    #pragma unroll
    for (int rep = 0; rep < 4; ++rep) {
        int idx  = rep * 256 + tid;
        int mat2 = idx >> 9;
        int row  = (idx >> 3) & 63;
        int seg  = idx & 7;
        short* dst = (short*)(ws + (mat2 ? KP_OFF : QP_OFF))
                     + (size_t)br * REG_ELEMS + (size_t)(n0 + row) * 64
                     + (seg ^ (row & 7)) * 8;
        *(uint4*)dst = *(uint4*)&trans[mat2][row][seg * 8];
    }
}

// ------------------------------------------------------------------ k_stats
// (r13 green m-split verbatim)
__global__ __launch_bounds__(256, 2) void k_stats(char* __restrict__ ws)
{
    const int tid  = threadIdx.x;
    const int br   = blockIdx.x & 7;
    const int nt   = (blockIdx.x >> 3) & 63;
    const int ms   = blockIdx.x >> 9;          // m-half
    const int lane = tid & 63;
    const int w    = tid >> 6;
    const int wn   = w & 1;
    const int wi   = w >> 1;
    const int col  = lane & 31;
    const int l5   = lane >> 5;

    const short* Qb  = (const short*)(ws + QP_OFF) + (size_t)br * REG_ELEMS;
    const char*  Kbb = ws + KP_OFF + (size_t)br * REG_ELEMS * 2
                       + (size_t)ms * 262144;  // 2048 rows * 128 B

    __shared__ __align__(16) char smem[16896];  // dbuf 16K | Lred 512

    const int nrow = nt * 64 + wn * 32 + col;
    bf16x8 afr[4];
    #pragma unroll
    for (int s = 0; s < 4; ++s)
        afr[s] = *(const bf16x8*)(Qb + (size_t)nrow * 64 + (((2*s+l5) ^ (col & 7)) * 8));

    float sm[16];
    #pragma unroll
    for (int r = 0; r < 16; ++r) sm[r] = 0.f;

    {   // stage slab 0 (64 m-rows = 8 KB; wave w covers 2 KB)
        const char* g = Kbb + (size_t)w * 2048 + lane * 16;
        char* l = smem + w * 2048;
        stage16(g, l); stage16(g + 1024, l + 1024);
    }

    #pragma unroll 2
    for (int slab = 0; slab < 32; ++slab) {
        __syncthreads();
        if (slab + 1 < 32) {
            const char* g = Kbb + (size_t)(slab + 1) * 8192 + w * 2048 + lane * 16;
            char* l = smem + ((slab + 1) & 1) * 8192 + w * 2048;
            stage16(g, l); stage16(g + 1024, l + 1024);
        }
        const short* Ks = (const short*)(smem + (slab & 1) * 8192);
        f32x16 d = zero16();
        #pragma unroll
        for (int s = 0; s < 4; ++s) {
            bf16x8 bf = *(const bf16x8*)(Ks + (wi * 32 + col) * 64
                                         + ((2*s+l5) ^ (col & 7)) * 8);
            d = MFMA32(afr[s], bf, d);
        }
        #pragma unroll
        for (int r = 0; r < 16; ++r) sm[r] += fexp2(d[r]);
    }

    #pragma unroll
    for (int off = 1; off < 32; off <<= 1)
        #pragma unroll
        for (int r = 0; r < 16; ++r) sm[r] += __shfl_xor(sm[r], off);

    __syncthreads();
    float* Lred = (float*)(smem + 16384);      // [4][32]
    if (col == 0) {
        #pragma unroll
        for (int r = 0; r < 16; ++r)
            Lred[w * 32 + ((r & 3) + 8 * (r >> 2) + 4 * l5)] = sm[r];
    }
    __syncthreads();
    if (tid < 64) {
        int wn2 = tid >> 5, nl = tid & 31;
        float L = Lred[wn2 * 32 + nl] + Lred[(wn2 + 2) * 32 + nl];
        ((float*)(ws + LPART_OFF))[(size_t)ms * 32768 + (size_t)br * 4096
                                   + nt * 64 + tid] = L;
    }
}

// ------------------------------------------------------------------ k_ascale
// (r13 green verbatim)
__global__ __launch_bounds__(256) void k_ascale(char* __restrict__ ws)
{
    const int tid = threadIdx.x;
    const int br  = blockIdx.x & 7;
    const int nt  = blockIdx.x >> 3;           // 0..63

    __shared__ float Larr[64];

    if (tid < 64) {
        const float* Lp = (const float*)(ws + LPART_OFF);
        const size_t idx = (size_t)br * 4096 + nt * 64 + tid;
        float li = 1.0f / (Lp[idx] + Lp[32768 + idx]);
        Larr[tid] = li;
        ((float*)(ws + LNV_OFF))[idx] = li;
    }
    __syncthreads();

    short* Ab = (short*)(ws + ATL_OFF) + (size_t)br * REG_ELEMS + (size_t)nt * 4096;
    #pragma unroll
    for (int rep = 0; rep < 2; ++rep) {
        int id = rep * 256 + tid;              // 0..511 chunks of 16B
        int t = id >> 8, c = (id >> 2) & 63, s = id & 3;
        int sg = s ^ ((c >> 1) & 3);
        int jl = t * 32 + sg * 8;
        short* p = Ab + (size_t)t * 2048 + c * 32 + s * 8;
        uint4 v = *(uint4*)p;
        short* sp = (short*)&v;
        short o[8];
        #pragma unroll
        for (int e = 0; e < 8; ++e) o[e] = f2bf(bf2f(sp[e]) * Larr[jl + e]);
        *(uint4*)p = *(uint4*)o;
    }
}

// ------------------------------------------------------------------- k_attn
// (round-14 green verbatim) block = (br, mt of 64 m); 4 waves = (wj path) x
// (jsw j-half).  Each wave holds BOTH m-fragment sets (2x acc); one set of
// jr/ts reads serves both m-halves.  64 rounds, 2 slabs (32 KB) per round.
__global__ __launch_bounds__(256, 2) void k_attn(char* __restrict__ ws)
{
    const int tid  = threadIdx.x;
    const int br   = blockIdx.x & 7;
    const int mt   = blockIdx.x >> 3;          // 0..63, m-tile of 64
    const int lane = tid & 63;
    const int w    = tid >> 6;                 // 0..3
    const int wj   = w & 1;                    // path: 0 = G1*A', 1 = G2*B
    const int jsw  = w >> 1;                   // j-half this wave computes
    const int col  = lane & 31;
    const int l5   = lane >> 5;
    const bool hi  = (l5 != 0);

    const char* Qbb = ws + QP_OFF  + (size_t)br * REG_ELEMS * 2;
    const char* Kbb = ws + KP_OFF  + (size_t)br * REG_ELEMS * 2;
    const char* Abb = ws + ATL_OFF + (size_t)br * REG_ELEMS * 2;
    const char* Bbb = ws + BTL_OFF + (size_t)br * REG_ELEMS * 2;
    const float* Lnv = (const float*)(ws + LNV_OFF) + (size_t)br * 4096;
    short* OutPb    = (short*)(ws + OUTP_OFF) + (size_t)br * REG_ELEMS;

    __shared__ __align__(16) char smem[65536];  // dbuf 2 x (2 js x 16K); red overlay

    // both m-fragment sets (m-sub 0 and 1)
    const short* msrcb = (const short*)(wj == 0 ? Kbb : Qbb);
    bf16x8 mf[2][4];
    #pragma unroll
    for (int h = 0; h < 2; ++h) {
        const short* mr = msrcb + (size_t)(mt * 64 + h * 32 + col) * 64;
        #pragma unroll
        for (int s = 0; s < 4; ++s)
            mf[h][s] = *(const bf16x8*)(mr + ((2*s+l5) ^ (col & 7)) * 8);
    }

    f32x16 acc00 = zero16(), acc01 = zero16();  // m-sub0: cols 0-31 / 32-63
    f32x16 acc10 = zero16(), acc11 = zero16();  // m-sub1

    // wave w stages tensor (w&3) for BOTH j-halves (8 KB = 8 instr / round)
    const char* gsb = (w == 0) ? Qbb : (w == 1) ? Kbb : (w == 2) ? Abb : Bbb;

    {   // stage round 0
        #pragma unroll
        for (int h = 0; h < 2; ++h) {
            const char* g = gsb + (size_t)h * 262144 + lane * 16;
            char* l = smem + h * 16384 + w * 4096 + lane * 16;
            #pragma unroll
            for (int i = 0; i < 4; ++i) stage16(g + i * 1024, l + i * 1024);
        }
    }

    #pragma unroll 2
    for (int rnd = 0; rnd < 64; ++rnd) {
        __syncthreads();
        if (rnd + 1 < 64) {
            #pragma unroll
            for (int h = 0; h < 2; ++h) {
                const char* g = gsb + (size_t)h * 262144
                                + (size_t)(rnd + 1) * 4096 + lane * 16;
                char* l = smem + ((rnd + 1) & 1) * 32768 + h * 16384
                          + w * 4096 + lane * 16;
                #pragma unroll
                for (int i = 0; i < 4; ++i) stage16(g + i * 1024, l + i * 1024);
            }
        }
        const char* sb = smem + (rnd & 1) * 32768 + jsw * 16384;
        const short* jr = (const short*)(sb + (wj == 0 ? 0 : 4096));      // Q | K rows
        const short* ts = (const short*)(sb + (wj == 0 ? 8192 : 12288));  // A' | B tile

        // one set of jr reads serves both m-halves
        bf16x8 a[4];
        #pragma unroll
        for (int s = 0; s < 4; ++s)
            a[s] = *(const bf16x8*)(jr + col * 64 + ((2*s+l5) ^ (col & 7)) * 8);

        f32x16 d0 = zero16(), d1 = zero16();
        #pragma unroll
        for (int s = 0; s < 4; ++s) {
            d0 = MFMA32(a[s], mf[0][s], d0);
            d1 = MFMA32(a[s], mf[1][s], d1);
        }

        // raw exp2 weights (normalizers folded in A' / deferred via Linv[m])
        unsigned W0[8], W1[8];
        #pragma unroll
        for (int q = 0; q < 4; ++q) {
            W0[2*q]   = pack_trunc(fexp2(d0[4*q]),   fexp2(d0[4*q+1]));
            W0[2*q+1] = pack_trunc(fexp2(d0[4*q+2]), fexp2(d0[4*q+3]));
            W1[2*q]   = pack_trunc(fexp2(d1[4*q]),   fexp2(d1[4*q+1]));
            W1[2*q+1] = pack_trunc(fexp2(d1[4*q+2]), fexp2(d1[4*q+3]));
        }

        // transpose both weight sets; shared ts reads feed 4 out-MFMAs
        #pragma unroll
        for (int k16 = 0; k16 < 2; ++k16) {
            unsigned u0 = W0[4*k16+0], u1 = W0[4*k16+1];
            unsigned u2 = W0[4*k16+2], u3 = W0[4*k16+3];
            permswap32(u0, u2, hi);
            permswap32(u1, u3, hi);
            union { uint4 u; bf16x8 v; } fr0;
            fr0.u.x = u0; fr0.u.y = u1; fr0.u.z = u2; fr0.u.w = u3;

            unsigned v0 = W1[4*k16+0], v1 = W1[4*k16+1];
            unsigned v2 = W1[4*k16+2], v3 = W1[4*k16+3];
            permswap32(v0, v2, hi);
            permswap32(v1, v3, hi);
            union { uint4 u; bf16x8 v; } fr1;
            fr1.u.x = v0; fr1.u.y = v1; fr1.u.z = v2; fr1.u.w = v3;

            const int swz = ((2*k16 + l5) ^ ((col >> 1) & 3)) * 8;
            bf16x8 bL = *(const bf16x8*)(ts + col * 32 + swz);
            bf16x8 bH = *(const bf16x8*)(ts + (col + 32) * 32 + swz);
            acc00 = MFMA32(fr0.v, bL, acc00);
            acc01 = MFMA32(fr0.v, bH, acc01);
            acc10 = MFMA32(fr1.v, bL, acc10);
            acc11 = MFMA32(fr1.v, bH, acc11);
        }
    }

    // epilogue: f32 combine across waves (w0 write, w2 add, w1/w3 add*Linv)
    __syncthreads();
    float* red = (float*)smem;                 // [64][68]
    if (w == 0) {
        #pragma unroll
        for (int h = 0; h < 2; ++h)
            #pragma unroll
            for (int r = 0; r < 16; ++r) {
                int ml = h * 32 + (r & 3) + 8 * (r >> 2) + 4 * l5;
                red[ml * 68 + col]      = h ? acc10[r] : acc00[r];
                red[ml * 68 + 32 + col] = h ? acc11[r] : acc01[r];
            }
    }
    __syncthreads();
    if (w == 2) {
        #pragma unroll
        for (int h = 0; h < 2; ++h)
            #pragma unroll
            for (int r = 0; r < 16; ++r) {
                int ml = h * 32 + (r & 3) + 8 * (r >> 2) + 4 * l5;
                red[ml * 68 + col]      += h ? acc10[r] : acc00[r];
                red[ml * 68 + 32 + col] += h ? acc11[r] : acc01[r];
            }
    }
    __syncthreads();
    if (w == 1) {
        #pragma unroll
        for (int h = 0; h < 2; ++h)
            #pragma unroll
            for (int r = 0; r < 16; ++r) {
                int ml = h * 32 + (r & 3) + 8 * (r >> 2) + 4 * l5;
                float li = Lnv[mt * 64 + ml];
                red[ml * 68 + col]      += li * (h ? acc10[r] : acc00[r]);
                red[ml * 68 + 32 + col] += li * (h ? acc11[r] : acc01[r]);
            }
    }
    __syncthreads();
    if (w == 3) {
        #pragma unroll
        for (int h = 0; h < 2; ++h)
            #pragma unroll
            for (int r = 0; r < 16; ++r) {
                int ml = h * 32 + (r & 3) + 8 * (r >> 2) + 4 * l5;
                float li = Lnv[mt * 64 + ml];
                red[ml * 68 + col]      += li * (h ? acc10[r] : acc00[r]);
                red[ml * 68 + 32 + col] += li * (h ? acc11[r] : acc01[r]);
            }
    }
    __syncthreads();
    {
        const int m  = tid >> 2;
        const int c0 = (tid & 3) * 16;
        const float* rp = red + m * 68 + c0;
        uint4 p0, p1;
        p0.x = pack_trunc(rp[0],  rp[1]);  p0.y = pack_trunc(rp[2],  rp[3]);
        p0.z = pack_trunc(rp[4],  rp[5]);  p0.w = pack_trunc(rp[6],  rp[7]);
        p1.x = pack_trunc(rp[8],  rp[9]);  p1.y = pack_trunc(rp[10], rp[11]);
        p1.z = pack_trunc(rp[12], rp[13]); p1.w = pack_trunc(rp[14], rp[15]);
        short* orow = OutPb + (size_t)(mt * 64 + m) * 64 + c0;
        *(uint4*)orow       = p0;
        *(uint4*)(orow + 8) = p1;
    }
}

// --------------------------------------------------------------- k_conv_out
// (r13 green verbatim: 256-thread remap, single OutP)
__global__ __launch_bounds__(256) void k_conv_out(
    const char* __restrict__ ws,
    const float* __restrict__ Wo, const float* __restrict__ bo,
    float* __restrict__ out)
{
    const int tid  = threadIdx.x;
    const int lane = tid & 63;
    const int sub  = tid >> 6;                 // 0..3
    const int blk  = blockIdx.x;               // 0..255
    const int br   = blk & 7;
    const int nt   = (blk >> 3) * 4 + sub;     // 0..127
    const int col  = lane & 31;
    const int l5   = lane >> 5;

    const short* OutPb = (const short*)(ws + OUTP_OFF) + (size_t)br * REG_ELEMS;

    bf16x8 afr[4];
    const short* arow = OutPb + (size_t)(nt * 32 + col) * 64 + l5 * 8;
    #pragma unroll
    for (int s = 0; s < 4; ++s) afr[s] = *(const bf16x8*)(arow + s * 16);

    bf16x8 bw[2][4];
    #pragma unroll
    for (int oh = 0; oh < 2; ++oh) {
        const float* wrow = Wo + (size_t)(oh * 32 + col) * 64 + l5 * 8;
        #pragma unroll
        for (int s = 0; s < 4; ++s) {
            float4 f0 = *(const float4*)(wrow + s * 16);
            float4 f1 = *(const float4*)(wrow + s * 16 + 4);
            union { bf16x8 v; short sh[8]; } u;
            u.sh[0] = f2bf(f0.x); u.sh[1] = f2bf(f0.y);
            u.sh[2] = f2bf(f0.z); u.sh[3] = f2bf(f0.w);
            u.sh[4] = f2bf(f1.x); u.sh[5] = f2bf(f1.y);
            u.sh[6] = f2bf(f1.z); u.sh[7] = f2bf(f1.w);
            bw[oh][s] = u.v;
        }
    }

    f32x16 d0 = zero16(), d1 = zero16();
    #pragma unroll
    for (int s = 0; s < 4; ++s) {
        d0 = MFMA32(afr[s], bw[0][s], d0);
        d1 = MFMA32(afr[s], bw[1][s], d1);
    }

    const int b  = br >> 2;
    const int gi = (br >> 1) & 1;
    const int gj = br & 1;

    #pragma unroll
    for (int oh = 0; oh < 2; ++oh) {
        const int oc = oh * 32 + col;
        const float bias = bo[oc];
        const f32x16& d = oh ? d1 : d0;
        #pragma unroll
        for (int q = 0; q < 4; ++q) {
            int nloc = 8 * q + 4 * l5;
            int nreg = nt * 32 + nloc;
            int wp   = nreg & 63;
            int ip   = nreg >> 6;
            float4 v = make_float4(d[4*q+0] + bias, d[4*q+1] + bias,
                                   d[4*q+2] + bias, d[4*q+3] + bias);
            float* op = out + ((size_t)(b * 64 + oc)) * 16384
                        + (size_t)(gi * 64 + ip) * 128 + gj * 64 + wp;
            *(float4*)op = v;
        }
    }
}

// -------------------------------------------------------------------- launch
extern "C" void kernel_launch(void* const* d_in, const int* in_sizes, int n_in,
                              void* d_out, int out_size, void* d_ws, size_t ws_size,
                              hipStream_t stream)
{
    const float* x  = (const float*)d_in[0];
    const float* Wq = (const float*)d_in[1];
    const float* bq = (const float*)d_in[2];
    const float* Wk = (const float*)d_in[3];
    const float* bk = (const float*)d_in[4];
    const float* Wa = (const float*)d_in[5];
    const float* ba = (const float*)d_in[6];
    const float* Wb = (const float*)d_in[7];
    const float* bb = (const float*)d_in[8];
    const float* Wo = (const float*)d_in[9];
    const float* bo = (const float*)d_in[10];
    char* ws   = (char*)d_ws;
    float* out = (float*)d_out;

    hipLaunchKernelGGL(k_conv_in,  dim3(512),  dim3(256), 0, stream,
                       x, Wq, bq, Wk, bk, Wa, ba, Wb, bb, ws);
    hipLaunchKernelGGL(k_stats,    dim3(1024), dim3(256), 0, stream, ws);
    hipLaunchKernelGGL(k_ascale,   dim3(512),  dim3(256), 0, stream, ws);
    hipLaunchKernelGGL(k_attn,     dim3(512),  dim3(256), 0, stream, ws);
    hipLaunchKernelGGL(k_conv_out, dim3(256),  dim3(256), 0, stream,
                       ws, Wo, bo, out);
}